// Round 19
// baseline (77.736 us; speedup 1.0000x reference)
//
#include <hip/hip_runtime.h>

#define RES 128
#define NCELLS (RES * RES * RES)        // 2097152
#define CASC 4
#define GRID_TOTAL (CASC * NCELLS)      // 8388608 = 2^23
#define NBYTES (GRID_TOTAL / 8)         // 1048576
#define MAIN_BLOCKS (NCELLS / 1024)     // 2048: block = 1024 morton cells = 16x8x8 cube

typedef float f32x2 __attribute__((ext_vector_type(2)));

// inverse of instant-ngp expand_bits: gather every 3rd bit
__device__ __forceinline__ unsigned compact3(unsigned v) {
    v &= 0x49249249u;
    v = (v | (v >> 2))  & 0xC30C30C3u;
    v = (v | (v >> 4))  & 0x0F00F00Fu;
    v = (v | (v >> 8))  & 0xFF0000FFu;
    v = (v | (v >> 16)) & 0x3FFu;
    return v;
}

__device__ __forceinline__ f32x2 pk_fma(f32x2 a, f32x2 b, f32x2 c) {
    return __builtin_elementwise_fma(a, b, c);   // v_pk_fma_f32, IEEE fma per lane
}

// Block = 1024 consecutive morton cells = exact 16x8x8 cube (x:16, y:8, z:8).
// Per cascade phase: stage the cube's jitter (128 z-run segments x 96B = 12KB)
// into LDS via COALESCED linear loads, barrier, then compute 4 points/thread
// from LDS. Converts the 100MB demorton gather into streams. Math per cell is
// bit-identical to R17 (same fma order; f32x2 packs points instead of cascades).
__global__ __launch_bounds__(256) void dg_main(
    const float* __restrict__ dgrid,   // [CASC, NCELLS]
    const float* __restrict__ jit,     // [CASC, NCELLS, 3]
    const float* __restrict__ W1,      // [3,32]
    const float* __restrict__ b1,      // [32]
    const float* __restrict__ W2,      // [32]
    const float* __restrict__ b2,      // [1]
    float* __restrict__ out,           // [CASC, NCELLS]
    double* __restrict__ sum_ws)
{
    __shared__ float4 wq[32];          // {W1r0, W1r1, W1r2, b1}
    __shared__ float w2s[32];
    __shared__ double sdata[4];
    __shared__ float jl[3072];         // 12KB: one cascade's cube jitter

    const int tid = (int)threadIdx.x;
    if (tid < 32) {
        wq[tid] = make_float4(W1[tid], W1[32 + tid], W1[64 + tid], b1[tid]);
        w2s[tid] = W2[tid];
    }
    // (first stage barrier below also covers the weight writes)

    const int gid = blockIdx.x * 256 + tid;            // float4-group index
    const unsigned M0 = (unsigned)blockIdx.x * 1024u;  // block's morton base
    const unsigned X0 = compact3(M0);                  // multiple of 16
    const unsigned Y0 = compact3(M0 >> 1);             // multiple of 8
    const unsigned Z0 = compact3(M0 >> 2);             // multiple of 8

    // ---- phase-invariant staged-load offsets (global float idx within a cascade) ----
    // linear LDS idx i = r*256+tid; seg = i/24 (z-run), f = i%24
    int goff[12];
    #pragma unroll
    for (int r = 0; r < 12; ++r) {
        const int i = r * 256 + tid;
        const int seg = i / 24;
        const int f = i - seg * 24;
        const unsigned lx = (unsigned)seg >> 3;
        const unsigned ly = (unsigned)seg & 7u;
        const unsigned cb = ((X0 + lx) << 14) | ((Y0 + ly) << 7) | Z0;
        goff[r] = (int)(cb * 3u + (unsigned)f);
    }

    // ---- phase-invariant per-point LDS offsets + cell coords ----
    int loff[4];
    float cxk[4], cyk[4], czk[4];
    #pragma unroll
    for (int k = 0; k < 4; ++k) {
        const unsigned tp = (unsigned)(tid * 4 + k);   // local morton (0..1023)
        const unsigned lx = compact3(tp);              // 0..15
        const unsigned ly = compact3(tp >> 1);         // 0..7
        const unsigned lz = compact3(tp >> 2);         // 0..7
        loff[k] = (int)(lx * 192u + ly * 24u + lz * 3u);
        cxk[k] = (float)(X0 + lx);
        cyk[k] = (float)(Y0 + ly);
        czk[k] = (float)(Z0 + lz);
    }

    const float bb2 = b2[0];
    const float4* dg4 = (const float4*)dgrid;
    float4* o4 = (float4*)out;
    const f32x2 zer = {0.0f, 0.0f};
    double lsum = 0.0;

    #pragma unroll 1
    for (int L = 0; L < 4; ++L) {
        const float scale = (float)(1 << L);
        const size_t lbase = (size_t)L * ((size_t)NCELLS * 3);

        if (L) __syncthreads();        // all reads of jl from phase L-1 done
        #pragma unroll
        for (int r = 0; r < 12; ++r)
            jl[r * 256 + tid] = jit[lbase + (size_t)goff[r]];
        __syncthreads();               // staging (and weights, first pass) visible

        const float4 g4 = dg4[(size_t)L * (NCELLS / 4) + gid];

        // jitter for 4 points from LDS
        float jxk[4], jyk[4], jzk[4];
        #pragma unroll
        for (int k = 0; k < 4; ++k) {
            jxk[k] = jl[loff[k]];
            jyk[k] = jl[loff[k] + 1];
            jzk[k] = jl[loff[k] + 2];
        }

        // positions (identical op order to reference); pack points {0,1} and {2,3}
        const f32x2 pxA = { ((cxk[0] + jxk[0]) * (1.0f / 128.0f) - 0.5f) * scale,
                            ((cxk[1] + jxk[1]) * (1.0f / 128.0f) - 0.5f) * scale };
        const f32x2 pxB = { ((cxk[2] + jxk[2]) * (1.0f / 128.0f) - 0.5f) * scale,
                            ((cxk[3] + jxk[3]) * (1.0f / 128.0f) - 0.5f) * scale };
        const f32x2 pyA = { ((cyk[0] + jyk[0]) * (1.0f / 128.0f) - 0.5f) * scale,
                            ((cyk[1] + jyk[1]) * (1.0f / 128.0f) - 0.5f) * scale };
        const f32x2 pyB = { ((cyk[2] + jyk[2]) * (1.0f / 128.0f) - 0.5f) * scale,
                            ((cyk[3] + jyk[3]) * (1.0f / 128.0f) - 0.5f) * scale };
        const f32x2 pzA = { ((czk[0] + jzk[0]) * (1.0f / 128.0f) - 0.5f) * scale,
                            ((czk[1] + jzk[1]) * (1.0f / 128.0f) - 0.5f) * scale };
        const f32x2 pzB = { ((czk[2] + jzk[2]) * (1.0f / 128.0f) - 0.5f) * scale,
                            ((czk[3] + jzk[3]) * (1.0f / 128.0f) - 0.5f) * scale };

        f32x2 accA = {bb2, bb2}, accB = {bb2, bb2};
        #pragma unroll 4
        for (int j = 0; j < 32; ++j) {
            const float4 w = wq[j];
            const float u = w2s[j];
            const f32x2 wx = {w.x, w.x}, wy = {w.y, w.y}, wz = {w.z, w.z};
            const f32x2 wb = {w.w, w.w}, uu = {u, u};
            f32x2 hA = pk_fma(pxA, wx, wb);
            f32x2 hB = pk_fma(pxB, wx, wb);
            hA = pk_fma(pyA, wy, hA);
            hB = pk_fma(pyB, wy, hB);
            hA = pk_fma(pzA, wz, hA);
            hB = pk_fma(pzB, wz, hB);
            hA = __builtin_elementwise_max(hA, zer);
            hB = __builtin_elementwise_max(hB, zer);
            accA = pk_fma(hA, uu, accA);
            accB = pk_fma(hB, uu, accB);
        }

        // tail: softplus, EMA-max merge, accumulate, one float4 store
        const float aa[4] = {accA.x, accA.y, accB.x, accB.y};
        const float gg[4] = {g4.x, g4.y, g4.z, g4.w};
        float nn[4];
        #pragma unroll
        for (int k = 0; k < 4; ++k) {
            const float a = aa[k];
            const float d = fmaxf(a, 0.0f) + log1pf(expf(-fabsf(a)));
            const float g = gg[k];
            nn[k] = (g >= 0.0f && d >= 0.0f) ? fmaxf(g * 0.95f, d) : g;
            lsum += (double)nn[k];
        }
        o4[(size_t)L * (NCELLS / 4) + gid] = make_float4(nn[0], nn[1], nn[2], nn[3]);
    }

    // wave-level f64 reduction -> 4 LDS partials -> one atomic per block
    #pragma unroll
    for (int s = 32; s > 0; s >>= 1) lsum += __shfl_down(lsum, s);
    const int wid = tid >> 6;
    const int lane = tid & 63;
    if (lane == 0) sdata[wid] = lsum;
    __syncthreads();
    if (tid == 0)
        atomicAdd(sum_ws, (sdata[0] + sdata[1]) + (sdata[2] + sdata[3]));
}

// One thread per output byte. mean = sum * 2^-23 (bit-exact vs /GRID_TOTAL).
__global__ __launch_bounds__(256) void dg_bitfield(
    const float* __restrict__ grid,
    const double* __restrict__ sum_ws,
    float* __restrict__ outb,
    float* __restrict__ mean_out)
{
    const int i = blockIdx.x * 256 + threadIdx.x;
    const double mean = *sum_ws * (1.0 / (double)GRID_TOTAL);
    const float mf = (float)mean;
    if (i == 0) mean_out[0] = mf;
    const float t = fminf(mf, 2.0f);
    const float4* p = (const float4*)(grid + (size_t)i * 8);
    const float4 a = p[0];
    const float4 b = p[1];
    int v = 0;
    v |= (a.x > t) ? 1   : 0;
    v |= (a.y > t) ? 2   : 0;
    v |= (a.z > t) ? 4   : 0;
    v |= (a.w > t) ? 8   : 0;
    v |= (b.x > t) ? 16  : 0;
    v |= (b.y > t) ? 32  : 0;
    v |= (b.z > t) ? 64  : 0;
    v |= (b.w > t) ? 128 : 0;
    outb[i] = (float)v;
}

extern "C" void kernel_launch(void* const* d_in, const int* in_sizes, int n_in,
                              void* d_out, int out_size, void* d_ws, size_t ws_size,
                              hipStream_t stream) {
    const float* dgrid = (const float*)d_in[0];
    const float* jit   = (const float*)d_in[1];
    const float* W1    = (const float*)d_in[2];
    const float* b1    = (const float*)d_in[3];
    const float* W2    = (const float*)d_in[4];
    const float* b2    = (const float*)d_in[5];

    float* out = (float*)d_out;
    double* sum_ws = (double*)d_ws;

    hipMemsetAsync(d_ws, 0, 8, stream);   // zero the f64 accumulator (capture-safe)

    dg_main<<<MAIN_BLOCKS, 256, 0, stream>>>(dgrid, jit, W1, b1, W2, b2, out, sum_ws);
    dg_bitfield<<<NBYTES / 256, 256, 0, stream>>>(out, sum_ws,
                                                  out + GRID_TOTAL + 1,
                                                  out + GRID_TOTAL);
}

// Round 20
// 65.240 us; speedup vs baseline: 1.1915x; 1.1915x over previous
//
#include <hip/hip_runtime.h>

#define RES 128
#define NCELLS (RES * RES * RES)        // 2097152
#define CASC 4
#define GRID_TOTAL (CASC * NCELLS)      // 8388608 = 2^23
#define NBYTES (GRID_TOTAL / 8)         // 1048576
#define MAIN_BLOCKS (NCELLS / (256 * 4))     // 2048 (4 consecutive morton/thread)

typedef float f32x2 __attribute__((ext_vector_type(2)));

struct f3v { float x, y, z; };
__device__ __forceinline__ f3v load3(const float* __restrict__ p) {
    f3v v;
    __builtin_memcpy(&v, p, sizeof(f3v));   // -> global_load_dwordx3 (12B, 4B-aligned)
    return v;
}

// inverse of instant-ngp expand_bits: gather every 3rd bit
__device__ __forceinline__ unsigned compact3(unsigned v) {
    v &= 0x49249249u;
    v = (v | (v >> 2))  & 0xC30C30C3u;
    v = (v | (v >> 4))  & 0x0F00F00Fu;
    v = (v | (v >> 8))  & 0xFF0000FFu;
    v = (v | (v >> 16)) & 0x3FFu;
    return v;
}

__device__ __forceinline__ f32x2 pk_fma(f32x2 a, f32x2 b, f32x2 c) {
    return __builtin_elementwise_fma(a, b, c);   // v_pk_fma_f32, IEEE fma per lane
}

// fast softplus: hardware v_exp_f32 / v_log_f32 (~8 instrs vs libm's ~50).
// abs error ~1e-6 — well inside the pipeline's existing 0.0156 slack vs ref.
__device__ __forceinline__ float fast_softplus(float a) {
    return fmaxf(a, 0.0f) + __logf(1.0f + __expf(-fabsf(a)));
}

// 2048 blocks x 256 threads; thread gid handles morton m = gid*4 + {0,1,2,3}.
// R17 structure (proven 76.1us): dwordx3 jitter, float4 dgrid/out, j-outer
// weight loop. This round: softplus via HW transcendentals (VALU-bound fix).
__global__ __launch_bounds__(256) void dg_main(
    const float* __restrict__ dgrid,   // [CASC, NCELLS]
    const float* __restrict__ jit,     // [CASC, NCELLS, 3]
    const float* __restrict__ W1,      // [3,32]
    const float* __restrict__ b1,      // [32]
    const float* __restrict__ W2,      // [32]
    const float* __restrict__ b2,      // [1]
    float* __restrict__ out,           // [CASC, NCELLS]
    double* __restrict__ sum_ws)
{
    // wq[j] = {W1[j], W1[32+j], W1[64+j], b1[j]};  w2s[j] = W2[j]
    __shared__ float4 wq[32];
    __shared__ float w2s[32];
    __shared__ double sdata[4];
    if (threadIdx.x < 32) {
        const int j = threadIdx.x;
        wq[j] = make_float4(W1[j], W1[32 + j], W1[64 + j], b1[j]);
        w2s[j] = W2[j];
    }
    __syncthreads();

    const float bb2 = b2[0];
    const int gid = blockIdx.x * 256 + (int)threadIdx.x;   // float4-group index
    const int m0 = gid * 4;

    // ---- coalesced float4 dgrid loads (one dwordx4 per cascade) ----
    const float4* dg4 = (const float4*)dgrid;
    const float4 g4_0 = dg4[(size_t)0 * (NCELLS / 4) + gid];
    const float4 g4_1 = dg4[(size_t)1 * (NCELLS / 4) + gid];
    const float4 g4_2 = dg4[(size_t)2 * (NCELLS / 4) + gid];
    const float4 g4_3 = dg4[(size_t)3 * (NCELLS / 4) + gid];

    // ---- per-point coords, dwordx3 jitter loads, packed positions ----
#define PREP(K) \
    const int m_##K = m0 + K; \
    const unsigned x_##K = compact3((unsigned)m_##K); \
    const unsigned y_##K = compact3((unsigned)m_##K >> 1); \
    const unsigned z_##K = compact3((unsigned)m_##K >> 2); \
    const size_t jb_##K = ((size_t)((x_##K << 14) | (y_##K << 7) | z_##K)) * 3; \
    const float cx_##K = (float)x_##K, cy_##K = (float)y_##K, cz_##K = (float)z_##K; \
    const f3v ja_##K = load3(jit + jb_##K);                        /* cascade 0 */ \
    const f3v jb2_##K = load3(jit + (size_t)NCELLS * 3 + jb_##K);  /* cascade 1 */ \
    const f3v jc_##K = load3(jit + (size_t)NCELLS * 6 + jb_##K);   /* cascade 2 */ \
    const f3v jd_##K = load3(jit + (size_t)NCELLS * 9 + jb_##K);   /* cascade 3 */ \
    const f32x2 pxA_##K = { ((cx_##K + ja_##K.x) * (1.0f / 128.0f) - 0.5f) * 1.0f, \
                            ((cx_##K + jb2_##K.x) * (1.0f / 128.0f) - 0.5f) * 2.0f }; \
    const f32x2 pxB_##K = { ((cx_##K + jc_##K.x) * (1.0f / 128.0f) - 0.5f) * 4.0f, \
                            ((cx_##K + jd_##K.x) * (1.0f / 128.0f) - 0.5f) * 8.0f }; \
    const f32x2 pyA_##K = { ((cy_##K + ja_##K.y) * (1.0f / 128.0f) - 0.5f) * 1.0f, \
                            ((cy_##K + jb2_##K.y) * (1.0f / 128.0f) - 0.5f) * 2.0f }; \
    const f32x2 pyB_##K = { ((cy_##K + jc_##K.y) * (1.0f / 128.0f) - 0.5f) * 4.0f, \
                            ((cy_##K + jd_##K.y) * (1.0f / 128.0f) - 0.5f) * 8.0f }; \
    const f32x2 pzA_##K = { ((cz_##K + ja_##K.z) * (1.0f / 128.0f) - 0.5f) * 1.0f, \
                            ((cz_##K + jb2_##K.z) * (1.0f / 128.0f) - 0.5f) * 2.0f }; \
    const f32x2 pzB_##K = { ((cz_##K + jc_##K.z) * (1.0f / 128.0f) - 0.5f) * 4.0f, \
                            ((cz_##K + jd_##K.z) * (1.0f / 128.0f) - 0.5f) * 8.0f }; \
    f32x2 accA_##K = {bb2, bb2}, accB_##K = {bb2, bb2};

    PREP(0) PREP(1) PREP(2) PREP(3)
#undef PREP

    const f32x2 zer = {0.0f, 0.0f};

    // ---- j-outer MLP: one weight fetch per j feeds 8 chains (16 cells) ----
#define STEP(K) { \
        f32x2 hA = pk_fma(pxA_##K, wx, wb); \
        f32x2 hB = pk_fma(pxB_##K, wx, wb); \
        hA = pk_fma(pyA_##K, wy, hA); \
        hB = pk_fma(pyB_##K, wy, hB); \
        hA = pk_fma(pzA_##K, wz, hA); \
        hB = pk_fma(pzB_##K, wz, hB); \
        hA = __builtin_elementwise_max(hA, zer); \
        hB = __builtin_elementwise_max(hB, zer); \
        accA_##K = pk_fma(hA, uu, accA_##K); \
        accB_##K = pk_fma(hB, uu, accB_##K); }

    #pragma unroll 4
    for (int j = 0; j < 32; ++j) {
        const float4 w = wq[j];
        const float u = w2s[j];
        const f32x2 wx = {w.x, w.x}, wy = {w.y, w.y}, wz = {w.z, w.z};
        const f32x2 wb = {w.w, w.w}, uu = {u, u};
        STEP(0) STEP(1) STEP(2) STEP(3)
    }
#undef STEP

    double lsum = 0.0;
    float n0_0, n0_1, n0_2, n0_3;   // results: n<level>_<k>
    float n1_0, n1_1, n1_2, n1_3;
    float n2_0, n2_1, n2_2, n2_3;
    float n3_0, n3_1, n3_2, n3_3;

#define TAIL(K, C) { \
    const float a0 = accA_##K.x; \
    const float d0 = fast_softplus(a0); \
    const float g0 = g4_0.C; \
    n0_##K = (g0 >= 0.0f && d0 >= 0.0f) ? fmaxf(g0 * 0.95f, d0) : g0; \
    lsum += (double)n0_##K; \
    const float a1 = accA_##K.y; \
    const float d1 = fast_softplus(a1); \
    const float g1 = g4_1.C; \
    n1_##K = (g1 >= 0.0f && d1 >= 0.0f) ? fmaxf(g1 * 0.95f, d1) : g1; \
    lsum += (double)n1_##K; \
    const float a2 = accB_##K.x; \
    const float d2 = fast_softplus(a2); \
    const float g2 = g4_2.C; \
    n2_##K = (g2 >= 0.0f && d2 >= 0.0f) ? fmaxf(g2 * 0.95f, d2) : g2; \
    lsum += (double)n2_##K; \
    const float a3 = accB_##K.y; \
    const float d3 = fast_softplus(a3); \
    const float g3 = g4_3.C; \
    n3_##K = (g3 >= 0.0f && d3 >= 0.0f) ? fmaxf(g3 * 0.95f, d3) : g3; \
    lsum += (double)n3_##K; }

    TAIL(0, x) TAIL(1, y) TAIL(2, z) TAIL(3, w)
#undef TAIL

    // ---- coalesced float4 stores (one dwordx4 per cascade) ----
    float4* o4 = (float4*)out;
    o4[(size_t)0 * (NCELLS / 4) + gid] = make_float4(n0_0, n0_1, n0_2, n0_3);
    o4[(size_t)1 * (NCELLS / 4) + gid] = make_float4(n1_0, n1_1, n1_2, n1_3);
    o4[(size_t)2 * (NCELLS / 4) + gid] = make_float4(n2_0, n2_1, n2_2, n2_3);
    o4[(size_t)3 * (NCELLS / 4) + gid] = make_float4(n3_0, n3_1, n3_2, n3_3);

    // wave-level f64 reduction -> 4 LDS partials -> one atomic per block
    #pragma unroll
    for (int s = 32; s > 0; s >>= 1) lsum += __shfl_down(lsum, s);
    const int wid = threadIdx.x >> 6;
    const int lane = threadIdx.x & 63;
    if (lane == 0) sdata[wid] = lsum;
    __syncthreads();
    if (threadIdx.x == 0)
        atomicAdd(sum_ws, (sdata[0] + sdata[1]) + (sdata[2] + sdata[3]));
}

// One thread per output byte. mean = sum * 2^-23 (bit-exact vs /GRID_TOTAL).
__global__ __launch_bounds__(256) void dg_bitfield(
    const float* __restrict__ grid,
    const double* __restrict__ sum_ws,
    float* __restrict__ outb,
    float* __restrict__ mean_out)
{
    const int i = blockIdx.x * 256 + threadIdx.x;
    const double mean = *sum_ws * (1.0 / (double)GRID_TOTAL);
    const float mf = (float)mean;
    if (i == 0) mean_out[0] = mf;
    const float t = fminf(mf, 2.0f);
    const float4* p = (const float4*)(grid + (size_t)i * 8);
    const float4 a = p[0];
    const float4 b = p[1];
    int v = 0;
    v |= (a.x > t) ? 1   : 0;
    v |= (a.y > t) ? 2   : 0;
    v |= (a.z > t) ? 4   : 0;
    v |= (a.w > t) ? 8   : 0;
    v |= (b.x > t) ? 16  : 0;
    v |= (b.y > t) ? 32  : 0;
    v |= (b.z > t) ? 64  : 0;
    v |= (b.w > t) ? 128 : 0;
    outb[i] = (float)v;
}

extern "C" void kernel_launch(void* const* d_in, const int* in_sizes, int n_in,
                              void* d_out, int out_size, void* d_ws, size_t ws_size,
                              hipStream_t stream) {
    const float* dgrid = (const float*)d_in[0];
    const float* jit   = (const float*)d_in[1];
    const float* W1    = (const float*)d_in[2];
    const float* b1    = (const float*)d_in[3];
    const float* W2    = (const float*)d_in[4];
    const float* b2    = (const float*)d_in[5];

    float* out = (float*)d_out;
    double* sum_ws = (double*)d_ws;

    hipMemsetAsync(d_ws, 0, 8, stream);   // zero the f64 accumulator (capture-safe)

    dg_main<<<MAIN_BLOCKS, 256, 0, stream>>>(dgrid, jit, W1, b1, W2, b2, out, sum_ws);
    dg_bitfield<<<NBYTES / 256, 256, 0, stream>>>(out, sum_ws,
                                                  out + GRID_TOTAL + 1,
                                                  out + GRID_TOTAL);
}